// Round 6
// baseline (557.602 us; speedup 1.0000x reference)
//
#include <hip/hip_runtime.h>

#define N_NODES 100000
#define N_EDGES 1200000
#define DIM     64
#define N_LAYERS 3
#define N_GRAPHS 512
#define OUTD    192   // 3 * 64, concat layout
#define BN_EPS  1e-5f

#define NPB 64            // nodes per block in mlp_kernel
#define LDS_PITCH 65      // +1 pad -> 2-way bank aliasing only (free)
#define NLBLK ((N_NODES + NPB - 1) / NPB)                 // 1563
#define NGBLK ((N_NODES + 15) / 16)                       // 6250 gather blocks

// ---- two-level binning geometry ----
#define BSHIFT 9
#define BUCK_NODES (1 << BSHIFT)                          // 512 nodes / bucket
#define NBUK ((N_NODES + BUCK_NODES - 1) / BUCK_NODES)    // 196
#define EPB 4096                                          // edges per partition block
#define NPBLK ((N_EDGES + EPB - 1) / EPB)                 // 293

// ---------------------------------------------------------------------------
// Transpose W1/W2 (per layer): WT[l][k][j] = W[l][j][k]. Also writes the
// identity affine block (scale=1, shift=0) used by layer 0.
__global__ void transpose_w(const float* __restrict__ W1, const float* __restrict__ W2,
                            float* __restrict__ W1T, float* __restrict__ W2T,
                            float* __restrict__ idaff) {
    int idx = blockIdx.x * blockDim.x + threadIdx.x;  // L*64*64
    if (idx < 128) idaff[idx] = (idx < 64) ? 1.0f : 0.0f;
    if (idx >= N_LAYERS * DIM * DIM) return;
    int l = idx >> 12;
    int r = idx & 4095;
    int j = r >> 6;
    int k = r & 63;
    int dstp = (l << 12) + k * DIM + j;
    W1T[dstp] = W1[idx];
    W2T[dstp] = W2[idx];
}

// ---------------------------------------------------------------------------
// Phase A: per-block bucket histogram (LDS atomics) + global bucket totals.
__global__ void __launch_bounds__(256) part_hist(const int* __restrict__ dst,
                                                 int* __restrict__ hist,
                                                 int* __restrict__ tot) {
    __shared__ int h[NBUK];
    int t = threadIdx.x;
    if (t < NBUK) h[t] = 0;
    __syncthreads();
    int base = blockIdx.x * EPB;
    for (int i = t; i < EPB; i += 256) {
        int e = base + i;
        if (e < N_EDGES) atomicAdd(&h[dst[e] >> BSHIFT], 1);
    }
    __syncthreads();
    if (t < NBUK) {
        int v = h[t];
        hist[blockIdx.x * NBUK + t] = v;
        if (v) atomicAdd(&tot[t], v);
    }
}

// ---------------------------------------------------------------------------
// Phase B1: scan 196 bucket totals -> bucket starts. One tiny block.
__global__ void __launch_bounds__(256) scan196(const int* __restrict__ tot,
                                               int* __restrict__ bstart) {
    __shared__ int lds[256];
    int t = threadIdx.x;
    int v = (t < NBUK) ? tot[t] : 0;
    lds[t] = v;
    __syncthreads();
    for (int o = 1; o < 256; o <<= 1) {
        int add = (t >= o) ? lds[t - o] : 0;
        __syncthreads();
        lds[t] += add;
        __syncthreads();
    }
    if (t < NBUK) bstart[t] = lds[t] - v;   // exclusive
    if (t == 0) bstart[NBUK] = N_EDGES;
}

// ---------------------------------------------------------------------------
// Phase B2: per-(block,bucket) bases. Block b scans hist column b.
__global__ void __launch_bounds__(256) base_fill(const int* __restrict__ hist,
                                                 const int* __restrict__ bstart,
                                                 int* __restrict__ base) {
    __shared__ int c[512];
    __shared__ int ssum[256];
    int b = blockIdx.x, t = threadIdx.x;
    c[t] = (t < NPBLK) ? hist[t * NBUK + b] : 0;
    c[t + 256] = (t + 256 < NPBLK) ? hist[(t + 256) * NBUK + b] : 0;
    __syncthreads();
    int c0 = c[2 * t], c1 = c[2 * t + 1];
    int ps = c0 + c1;
    ssum[t] = ps;
    __syncthreads();
    int v = ps;
    for (int o = 1; o < 256; o <<= 1) {
        int add = (t >= o) ? ssum[t - o] : 0;
        __syncthreads();
        ssum[t] += add;
        __syncthreads();
    }
    int excl = ssum[t] - v + bstart[b];     // exclusive over pairs + bucket base
    if (2 * t < NPBLK)     base[(2 * t) * NBUK + b] = excl;
    if (2 * t + 1 < NPBLK) base[(2 * t + 1) * NBUK + b] = excl + c0;
}

// ---------------------------------------------------------------------------
// Phase C: scatter edges into bucket-partitioned order.
__global__ void __launch_bounds__(256) part_scatter(
        const int* __restrict__ src, const int* __restrict__ dst,
        const float* __restrict__ ew, const int* __restrict__ base,
        int2* __restrict__ pp) {
    __shared__ int cur[NBUK];
    int t = threadIdx.x;
    if (t < NBUK) cur[t] = base[blockIdx.x * NBUK + t];
    __syncthreads();
    int bb = blockIdx.x * EPB;
    for (int i = t; i < EPB; i += 256) {
        int e = bb + i;
        if (e < N_EDGES) {
            int d = dst[e];
            int bk = d >> BSHIFT;
            int pos = atomicAdd(&cur[bk], 1);
            int dl = d & (BUCK_NODES - 1);
            pp[pos] = make_int2(src[e] | (dl << 17), __float_as_int(ew[e]));
        }
    }
}

// ---------------------------------------------------------------------------
// Phase D: per-bucket counting sort -> CSR (writes L2-resident ~48KB window).
__global__ void __launch_bounds__(256) csr_build(
        const int2* __restrict__ pp, const int* __restrict__ bstart,
        int* __restrict__ seg, int2* __restrict__ pe) {
    __shared__ int cnt[BUCK_NODES];
    __shared__ int ssum[256];
    int b = blockIdx.x, t = threadIdx.x;
    int ebeg = bstart[b], eend = bstart[b + 1];
    cnt[t] = 0;
    cnt[t + 256] = 0;
    __syncthreads();
    for (int e = ebeg + t; e < eend; e += 256)
        atomicAdd(&cnt[pp[e].x >> 17], 1);
    __syncthreads();
    int c0 = cnt[2 * t], c1 = cnt[2 * t + 1];
    int ps = c0 + c1;
    ssum[t] = ps;
    __syncthreads();
    int v = ps;
    for (int o = 1; o < 256; o <<= 1) {
        int add = (t >= o) ? ssum[t - o] : 0;
        __syncthreads();
        ssum[t] += add;
        __syncthreads();
    }
    int excl = ssum[t] - v;           // exclusive over pairs
    int o0 = ebeg + excl;
    int o1 = o0 + c0;
    int n0 = (b << BSHIFT) + 2 * t;
    if (n0 < N_NODES) seg[n0] = o0;
    if (n0 + 1 < N_NODES) seg[n0 + 1] = o1;
    __syncthreads();                  // all cnt reads (c0,c1) retired
    cnt[2 * t] = o0;                  // reuse as cursors (global positions)
    cnt[2 * t + 1] = o1;
    __syncthreads();
    for (int e = ebeg + t; e < eend; e += 256) {
        int2 p = pp[e];
        int pos = atomicAdd(&cnt[p.x >> 17], 1);
        pe[pos] = make_int2(p.x & 0x1FFFF, p.y);   // plain (src, w)
    }
    if (b == 0 && t == 0) seg[N_NODES] = N_EDGES;
}

// ---------------------------------------------------------------------------
// GATHER kernel (split from MLP; R5 showed fused kernel latency-bound with
// perf ~ occupancy at VALUBusy 28%): one node per quarter-wave (16 lanes =
// 16 float4 cols), no LDS, no barriers -> occupancy capped only by VGPR.
// Per node: seg pair -> unroll-4 independent pe loads -> unroll-4
// independent 256B row loads -> fold self + input-BN affine -> one
// coalesced float4 store of the MLP-ready row.
__global__ void __launch_bounds__(256) gather_kernel(
    const float* __restrict__ x_in, int xstride,
    const int* __restrict__ seg, const int2* __restrict__ pe,
    const float* __restrict__ affine /* [128]: scale|shift */,
    float* __restrict__ agg /* [N][64] */) {
    int t = threadIdx.x;
    int col = t & 15;
    int n = blockIdx.x * 16 + (t >> 4);
    if (n >= N_NODES) return;
    const float4* aff4 = (const float4*)affine;
    float4 sc4 = aff4[col];
    float4 sh4 = aff4[16 + col];
    int beg = seg[n], end = seg[n + 1];
    float4 self = ((const float4*)(x_in + (size_t)n * xstride))[col];
    float4 a0 = make_float4(0.f, 0.f, 0.f, 0.f);
    float4 a1 = a0, a2 = a0, a3 = a0;
    float w0s = 0.f, w1s = 0.f, w2s = 0.f, w3s = 0.f;
    int e = beg;
    for (; e + 4 <= end; e += 4) {
        int2 p0 = pe[e];     int2 p1 = pe[e + 1];
        int2 p2 = pe[e + 2]; int2 p3 = pe[e + 3];
        float w0 = __int_as_float(p0.y), w1 = __int_as_float(p1.y);
        float w2 = __int_as_float(p2.y), w3 = __int_as_float(p3.y);
        float4 v0 = ((const float4*)(x_in + (size_t)p0.x * xstride))[col];
        float4 v1 = ((const float4*)(x_in + (size_t)p1.x * xstride))[col];
        float4 v2 = ((const float4*)(x_in + (size_t)p2.x * xstride))[col];
        float4 v3 = ((const float4*)(x_in + (size_t)p3.x * xstride))[col];
        a0.x = fmaf(w0, v0.x, a0.x); a0.y = fmaf(w0, v0.y, a0.y);
        a0.z = fmaf(w0, v0.z, a0.z); a0.w = fmaf(w0, v0.w, a0.w);
        a1.x = fmaf(w1, v1.x, a1.x); a1.y = fmaf(w1, v1.y, a1.y);
        a1.z = fmaf(w1, v1.z, a1.z); a1.w = fmaf(w1, v1.w, a1.w);
        a2.x = fmaf(w2, v2.x, a2.x); a2.y = fmaf(w2, v2.y, a2.y);
        a2.z = fmaf(w2, v2.z, a2.z); a2.w = fmaf(w2, v2.w, a2.w);
        a3.x = fmaf(w3, v3.x, a3.x); a3.y = fmaf(w3, v3.y, a3.y);
        a3.z = fmaf(w3, v3.z, a3.z); a3.w = fmaf(w3, v3.w, a3.w);
        w0s += w0; w1s += w1; w2s += w2; w3s += w3;
    }
    for (; e < end; ++e) {
        int2 p = pe[e];
        float w = __int_as_float(p.y);
        float4 v = ((const float4*)(x_in + (size_t)p.x * xstride))[col];
        a0.x = fmaf(w, v.x, a0.x); a0.y = fmaf(w, v.y, a0.y);
        a0.z = fmaf(w, v.z, a0.z); a0.w = fmaf(w, v.w, a0.w);
        w0s += w;
    }
    float4 s;
    s.x = (a0.x + a1.x) + (a2.x + a3.x);
    s.y = (a0.y + a1.y) + (a2.y + a3.y);
    s.z = (a0.z + a1.z) + (a2.z + a3.z);
    s.w = (a0.w + a1.w) + (a2.w + a3.w);
    float shw = 1.0f + ((w0s + w1s) + (w2s + w3s));
    float4 r;
    r.x = fmaf(sc4.x, s.x + self.x, sh4.x * shw);
    r.y = fmaf(sc4.y, s.y + self.y, sh4.y * shw);
    r.z = fmaf(sc4.z, s.z + self.z, sh4.z * shw);
    r.w = fmaf(sc4.w, s.w + self.w, sh4.w * shw);
    ((float4*)(agg + (size_t)n * DIM))[col] = r;
}

// ---------------------------------------------------------------------------
// MLP kernel: dense coalesced load of agg rows -> LDS -> GEMM1 -> relu ->
// GEMM2 -> relu -> out + BN stat partials. (R5 epilogue unchanged.)
__global__ void __launch_bounds__(256) mlp_kernel(
    const float* __restrict__ agg,
    const float* __restrict__ W1T, const float* __restrict__ b1,
    const float* __restrict__ W2T, const float* __restrict__ b2,
    float* __restrict__ out /* xs base + layer*64, row stride OUTD */,
    float* __restrict__ pstat /* [NLBLK][128] */) {
    __shared__ float lds[NPB * LDS_PITCH];
    int t = threadIdx.x;
    int lane = t & 63;
    int wid = __builtin_amdgcn_readfirstlane(t >> 6);   // wave id 0..3, SGPR
    int nbase = blockIdx.x * NPB;
    int nvalid = N_NODES - nbase;
    if (nvalid > NPB) nvalid = NPB;
    int limit4 = nvalid * 16;          // float4 count for this block

    const float4* ag4 = (const float4*)(agg + (size_t)nbase * DIM);
#pragma unroll
    for (int k = 0; k < 4; ++k) {
        int idx = t + k * 256;
        float4 v = (idx < limit4) ? ag4[idx] : make_float4(0.f, 0.f, 0.f, 0.f);
        int row = idx >> 4, c4 = idx & 15;
        int lb = row * LDS_PITCH + c4 * 4;
        lds[lb] = v.x; lds[lb + 1] = v.y; lds[lb + 2] = v.z; lds[lb + 3] = v.w;
    }
    __syncthreads();

    // ---- Stage 1 GEMM: hidden = relu(xin @ W1^T + b1) ----
    float h[16];
#pragma unroll
    for (int jj = 0; jj < 16; ++jj) h[jj] = b1[wid * 16 + jj];
#pragma unroll 4
    for (int k = 0; k < DIM; ++k) {
        float xv = lds[lane * LDS_PITCH + k];
        const float* wr = W1T + k * DIM + wid * 16;   // uniform -> s_load
#pragma unroll
        for (int jj = 0; jj < 16; ++jj) h[jj] = fmaf(xv, wr[jj], h[jj]);
    }
#pragma unroll
    for (int jj = 0; jj < 16; ++jj) h[jj] = fmaxf(h[jj], 0.0f);
    __syncthreads();          // all lds (xin) reads done
#pragma unroll
    for (int jj = 0; jj < 16; ++jj) lds[lane * LDS_PITCH + wid * 16 + jj] = h[jj];
    __syncthreads();

    // ---- Stage 2 GEMM: o = relu(hidden @ W2^T + b2) ----
    float o[16];
#pragma unroll
    for (int jj = 0; jj < 16; ++jj) o[jj] = b2[wid * 16 + jj];
#pragma unroll 4
    for (int k = 0; k < DIM; ++k) {
        float hv = lds[lane * LDS_PITCH + k];
        const float* wr = W2T + k * DIM + wid * 16;
#pragma unroll
        for (int jj = 0; jj < 16; ++jj) o[jj] = fmaf(hv, wr[jj], o[jj]);
    }
    int n = nbase + lane;
    bool valid = (n < N_NODES);
#pragma unroll
    for (int jj = 0; jj < 16; ++jj) o[jj] = fmaxf(o[jj], 0.0f);
    if (valid) {
        float* orow = out + (size_t)n * OUTD + wid * 16;
#pragma unroll
        for (int jj = 0; jj < 16; jj += 4) {
            *(float4*)(orow + jj) = make_float4(o[jj], o[jj + 1], o[jj + 2], o[jj + 3]);
        }
    }

    // ---- BN stat partials: butterfly over 64 lanes ----
    float my_s = 0.0f, my_q = 0.0f;
#pragma unroll
    for (int jj = 0; jj < 16; ++jj) {
        float v = valid ? o[jj] : 0.0f;
        float vs = v, vq = v * v;
#pragma unroll
        for (int m = 1; m < 64; m <<= 1) {
            vs += __shfl_xor(vs, m);
            vq += __shfl_xor(vq, m);
        }
        if (lane == jj) { my_s = vs; my_q = vq; }
    }
    if (lane < 16) {
        size_t base = (size_t)blockIdx.x * 128 + wid * 16 + lane;
        pstat[base] = my_s;
        pstat[base + 64] = my_q;
    }
}

// ---------------------------------------------------------------------------
// Reduce per-block BN partials -> scale/shift (bn_prep folded).
__global__ void __launch_bounds__(256) reduce_stats(
    const float* __restrict__ pstat,
    const float* __restrict__ gamma, const float* __restrict__ beta,
    float* __restrict__ ss /* [128]: scale|shift */) {
    __shared__ double part[16][16];
    int b = blockIdx.x;            // 0..7
    int t = threadIdx.x;
    int slot = t & 15;             // 0..7 -> sum(d), 8..15 -> sumsq(d)
    int g = t >> 4;                // group 0..15
    int d = b * 8 + (slot & 7);
    int off = (slot < 8) ? 0 : 64;
    double s = 0.0;
    for (int blk = g; blk < NLBLK; blk += 16)
        s += (double)pstat[(size_t)blk * 128 + off + d];
    part[g][slot] = s;
    __syncthreads();
    if (t < 16) {
        double x = 0.0;
#pragma unroll
        for (int k = 0; k < 16; ++k) x += part[k][t];
        part[0][t] = x;            // column t only -> no hazard
    }
    __syncthreads();
    if (t < 8) {
        int dd = b * 8 + t;
        double mu = part[0][t] / (double)N_NODES;
        double var = part[0][8 + t] / (double)N_NODES - mu * mu;
        float inv = (float)(1.0 / sqrt(var + (double)BN_EPS));
        float sc = gamma[dd] * inv;
        ss[dd] = sc;
        ss[64 + dd] = beta[dd] - (float)mu * sc;
    }
}

// ---------------------------------------------------------------------------
// Final pass: apply BN affine to xs IN PLACE (all 3 layers at once) and
// add-pool per graph. Grid (512 graphs, 4 parts), block 192.
__global__ void bn_pool(float* __restrict__ xs,
                        const int* __restrict__ batch,
                        const float* __restrict__ ss /* [3][128] */,
                        float* __restrict__ pooled) {
    int g = blockIdx.x;
    int part = blockIdx.y;   // 0..3
    int d = threadIdx.x;     // 0..191
    int l = d >> 6, dd = d & 63;
    float sc = ss[l * 128 + dd];
    float sh = ss[l * 128 + 64 + dd];
    int start, end;
    {
        int lo = 0, hi = N_NODES;
        while (lo < hi) { int m = (lo + hi) >> 1; if (batch[m] < g) lo = m + 1; else hi = m; }
        start = lo;
    }
    {
        int lo = start, hi = N_NODES;
        while (lo < hi) { int m = (lo + hi) >> 1; if (batch[m] <= g) lo = m + 1; else hi = m; }
        end = lo;
    }
    float acc = 0.0f;
    for (int n = start + part; n < end; n += 4) {
        float* p = xs + (size_t)n * OUTD + d;
        float v = fmaf(*p, sc, sh);
        *p = v;
        acc += v;
    }
    atomicAdd(&pooled[(size_t)g * OUTD + d], acc);
}

// ---------------------------------------------------------------------------
extern "C" void kernel_launch(void* const* d_in, const int* in_sizes, int n_in,
                              void* d_out, int out_size, void* d_ws, size_t ws_size,
                              hipStream_t stream) {
    const float* x0    = (const float*)d_in[0];
    const int*   ei    = (const int*)d_in[1];
    const float* ew    = (const float*)d_in[2];
    const int*   batch = (const int*)d_in[3];
    const float* W1    = (const float*)d_in[5];
    const float* b1    = (const float*)d_in[6];
    const float* W2    = (const float*)d_in[7];
    const float* b2    = (const float*)d_in[8];
    const float* gamma = (const float*)d_in[9];
    const float* beta  = (const float*)d_in[10];

    float* pooled = (float*)d_out;                      // [512, 192]
    float* xs     = pooled + (size_t)N_GRAPHS * OUTD;   // [100000, 192]

    const int* src = ei;
    const int* dst = ei + N_EDGES;

    // Workspace (~36.5 MB): head = persistent; tail union = {binning scratch}
    // overlapped with {agg} (binning finishes before first gather).
    int2*  pe     = (int2*)d_ws;                        // E          9.6 MB
    int*   seg    = (int*)(pe + N_EDGES);               // N+4
    int*   tot    = seg + N_NODES + 4;                  // NBUK+4
    int*   bstart = tot + NBUK + 4;                     // NBUK+4
    float* W1T    = (float*)(bstart + NBUK + 4);
    float* W2T    = W1T + N_LAYERS * DIM * DIM;
    float* idaff  = W2T + N_LAYERS * DIM * DIM;         // 128 floats
    float* ss     = idaff + 128;                        // 3*128 floats
    float* pstat  = ss + N_LAYERS * 128;                // NLBLK*128 floats
    // union region:
    float* uni    = pstat + (size_t)NLBLK * 128;
    int2*  pp     = (int2*)uni;                         // E (binning only)
    int*   hist   = (int*)(pp + N_EDGES);               // NPBLK*NBUK
    int*   pbase  = hist + (size_t)NPBLK * NBUK;        // NPBLK*NBUK
    float* agg    = uni;                                // N*64 (layers only)

    transpose_w<<<(N_LAYERS * DIM * DIM + 255) / 256, 256, 0, stream>>>(
        W1, W2, W1T, W2T, idaff);

    // Two-level binning: contention-free partition -> per-bucket CSR.
    hipMemsetAsync(tot, 0, (NBUK + 4) * sizeof(int), stream);
    part_hist<<<NPBLK, 256, 0, stream>>>(dst, hist, tot);
    scan196<<<1, 256, 0, stream>>>(tot, bstart);
    base_fill<<<NBUK, 256, 0, stream>>>(hist, bstart, pbase);
    part_scatter<<<NPBLK, 256, 0, stream>>>(src, dst, ew, pbase, pp);
    csr_build<<<NBUK, 256, 0, stream>>>(pp, bstart, seg, pe);

    for (int i = 0; i < N_LAYERS; ++i) {
        const float* xin = (i == 0) ? x0 : (xs + (size_t)(i - 1) * DIM);
        int xstride = (i == 0) ? DIM : OUTD;
        const float* affine = (i == 0) ? idaff : (ss + (size_t)(i - 1) * 128);

        gather_kernel<<<NGBLK, 256, 0, stream>>>(
            xin, xstride, seg, pe, affine, agg);

        mlp_kernel<<<NLBLK, 256, 0, stream>>>(
            agg,
            W1T + (size_t)i * DIM * DIM, b1 + (size_t)i * DIM,
            W2T + (size_t)i * DIM * DIM, b2 + (size_t)i * DIM,
            xs + (size_t)i * DIM, pstat);

        reduce_stats<<<8, 256, 0, stream>>>(
            pstat, gamma + (size_t)i * DIM, beta + (size_t)i * DIM,
            ss + (size_t)i * 128);
    }

    hipMemsetAsync(pooled, 0, (size_t)N_GRAPHS * OUTD * sizeof(float), stream);
    dim3 pgrid(N_GRAPHS, 4);
    bn_pool<<<pgrid, OUTD, 0, stream>>>(xs, batch, ss, pooled);
}

// Round 7
// 539.385 us; speedup vs baseline: 1.0338x; 1.0338x over previous
//
#include <hip/hip_runtime.h>

#define N_NODES 100000
#define N_EDGES 1200000
#define DIM     64
#define N_LAYERS 3
#define N_GRAPHS 512
#define OUTD    192   // 3 * 64, concat layout
#define BN_EPS  1e-5f

#define NPB 64            // nodes per block in layer_kernel
#define LDS_PITCH 65      // +1 pad -> 2-way bank aliasing only (free)
#define NLBLK ((N_NODES + NPB - 1) / NPB)                 // 1563

// ---- two-level binning geometry ----
#define BSHIFT 9
#define BUCK_NODES (1 << BSHIFT)                          // 512 nodes / bucket
#define NBUK ((N_NODES + BUCK_NODES - 1) / BUCK_NODES)    // 196
#define EPB 4096                                          // edges per partition block
#define NPBLK ((N_EDGES + EPB - 1) / EPB)                 // 293

__device__ __forceinline__ unsigned short f2bf(float f) {
    unsigned u = __float_as_uint(f);
    return (unsigned short)((u + 0x7FFFu + ((u >> 16) & 1u)) >> 16);   // RNE
}
__device__ __forceinline__ float bf2f(unsigned short h) {
    return __uint_as_float(((unsigned)h) << 16);
}

// ---------------------------------------------------------------------------
// Transpose W1/W2 (per layer): WT[l][k][j] = W[l][j][k]. Also writes the
// identity affine block (scale=1, shift=0) used by layer 0.
__global__ void transpose_w(const float* __restrict__ W1, const float* __restrict__ W2,
                            float* __restrict__ W1T, float* __restrict__ W2T,
                            float* __restrict__ idaff) {
    int idx = blockIdx.x * blockDim.x + threadIdx.x;  // L*64*64
    if (idx < 128) idaff[idx] = (idx < 64) ? 1.0f : 0.0f;
    if (idx >= N_LAYERS * DIM * DIM) return;
    int l = idx >> 12;
    int r = idx & 4095;
    int j = r >> 6;
    int k = r & 63;
    int dstp = (l << 12) + k * DIM + j;
    W1T[dstp] = W1[idx];
    W2T[dstp] = W2[idx];
}

// ---------------------------------------------------------------------------
// Convert x0 -> bf16 shadow (dense [N][64]).
__global__ void __launch_bounds__(256) to_bf16(const float* __restrict__ x,
                                               unsigned short* __restrict__ x16) {
    int i = blockIdx.x * blockDim.x + threadIdx.x;   // quad index, N*16
    if (i >= N_NODES * 16) return;
    float4 v = ((const float4*)x)[i];
    ushort4 r;
    r.x = f2bf(v.x); r.y = f2bf(v.y); r.z = f2bf(v.z); r.w = f2bf(v.w);
    ((ushort4*)x16)[i] = r;
}

// ---------------------------------------------------------------------------
// Phase A: per-block bucket histogram (LDS atomics) + global bucket totals.
__global__ void __launch_bounds__(256) part_hist(const int* __restrict__ dst,
                                                 int* __restrict__ hist,
                                                 int* __restrict__ tot) {
    __shared__ int h[NBUK];
    int t = threadIdx.x;
    if (t < NBUK) h[t] = 0;
    __syncthreads();
    int base = blockIdx.x * EPB;
    for (int i = t; i < EPB; i += 256) {
        int e = base + i;
        if (e < N_EDGES) atomicAdd(&h[dst[e] >> BSHIFT], 1);
    }
    __syncthreads();
    if (t < NBUK) {
        int v = h[t];
        hist[blockIdx.x * NBUK + t] = v;
        if (v) atomicAdd(&tot[t], v);
    }
}

// ---------------------------------------------------------------------------
// Phase B1: scan 196 bucket totals -> bucket starts. One tiny block.
__global__ void __launch_bounds__(256) scan196(const int* __restrict__ tot,
                                               int* __restrict__ bstart) {
    __shared__ int lds[256];
    int t = threadIdx.x;
    int v = (t < NBUK) ? tot[t] : 0;
    lds[t] = v;
    __syncthreads();
    for (int o = 1; o < 256; o <<= 1) {
        int add = (t >= o) ? lds[t - o] : 0;
        __syncthreads();
        lds[t] += add;
        __syncthreads();
    }
    if (t < NBUK) bstart[t] = lds[t] - v;   // exclusive
    if (t == 0) bstart[NBUK] = N_EDGES;
}

// ---------------------------------------------------------------------------
// Phase B2: per-(block,bucket) bases. Block b scans hist column b.
__global__ void __launch_bounds__(256) base_fill(const int* __restrict__ hist,
                                                 const int* __restrict__ bstart,
                                                 int* __restrict__ base) {
    __shared__ int c[512];
    __shared__ int ssum[256];
    int b = blockIdx.x, t = threadIdx.x;
    c[t] = (t < NPBLK) ? hist[t * NBUK + b] : 0;
    c[t + 256] = (t + 256 < NPBLK) ? hist[(t + 256) * NBUK + b] : 0;
    __syncthreads();
    int c0 = c[2 * t], c1 = c[2 * t + 1];
    int ps = c0 + c1;
    ssum[t] = ps;
    __syncthreads();
    int v = ps;
    for (int o = 1; o < 256; o <<= 1) {
        int add = (t >= o) ? ssum[t - o] : 0;
        __syncthreads();
        ssum[t] += add;
        __syncthreads();
    }
    int excl = ssum[t] - v + bstart[b];     // exclusive over pairs + bucket base
    if (2 * t < NPBLK)     base[(2 * t) * NBUK + b] = excl;
    if (2 * t + 1 < NPBLK) base[(2 * t + 1) * NBUK + b] = excl + c0;
}

// ---------------------------------------------------------------------------
// Phase C: scatter edges into bucket-partitioned order.
__global__ void __launch_bounds__(256) part_scatter(
        const int* __restrict__ src, const int* __restrict__ dst,
        const float* __restrict__ ew, const int* __restrict__ base,
        int2* __restrict__ pp) {
    __shared__ int cur[NBUK];
    int t = threadIdx.x;
    if (t < NBUK) cur[t] = base[blockIdx.x * NBUK + t];
    __syncthreads();
    int bb = blockIdx.x * EPB;
    for (int i = t; i < EPB; i += 256) {
        int e = bb + i;
        if (e < N_EDGES) {
            int d = dst[e];
            int bk = d >> BSHIFT;
            int pos = atomicAdd(&cur[bk], 1);
            int dl = d & (BUCK_NODES - 1);
            pp[pos] = make_int2(src[e] | (dl << 17), __float_as_int(ew[e]));
        }
    }
}

// ---------------------------------------------------------------------------
// Phase D: per-bucket counting sort -> CSR (writes L2-resident ~48KB window).
__global__ void __launch_bounds__(256) csr_build(
        const int2* __restrict__ pp, const int* __restrict__ bstart,
        int* __restrict__ seg, int2* __restrict__ pe) {
    __shared__ int cnt[BUCK_NODES];
    __shared__ int ssum[256];
    int b = blockIdx.x, t = threadIdx.x;
    int ebeg = bstart[b], eend = bstart[b + 1];
    cnt[t] = 0;
    cnt[t + 256] = 0;
    __syncthreads();
    for (int e = ebeg + t; e < eend; e += 256)
        atomicAdd(&cnt[pp[e].x >> 17], 1);
    __syncthreads();
    int c0 = cnt[2 * t], c1 = cnt[2 * t + 1];
    int ps = c0 + c1;
    ssum[t] = ps;
    __syncthreads();
    int v = ps;
    for (int o = 1; o < 256; o <<= 1) {
        int add = (t >= o) ? ssum[t - o] : 0;
        __syncthreads();
        ssum[t] += add;
        __syncthreads();
    }
    int excl = ssum[t] - v;           // exclusive over pairs
    int o0 = ebeg + excl;
    int o1 = o0 + c0;
    int n0 = (b << BSHIFT) + 2 * t;
    if (n0 < N_NODES) seg[n0] = o0;
    if (n0 + 1 < N_NODES) seg[n0 + 1] = o1;
    __syncthreads();                  // all cnt reads (c0,c1) retired
    cnt[2 * t] = o0;                  // reuse as cursors (global positions)
    cnt[2 * t + 1] = o1;
    __syncthreads();
    for (int e = ebeg + t; e < eend; e += 256) {
        int2 p = pp[e];
        int pos = atomicAdd(&cnt[p.x >> 17], 1);
        pe[pos] = make_int2(p.x & 0x1FFFF, p.y);   // plain (src, w)
    }
    if (b == 0 && t == 0) seg[N_NODES] = N_EDGES;
}

// ---------------------------------------------------------------------------
// Fused layer (R5 structure + bf16 neighbor rows): quarter-wave float4
// gather, but neighbor rows come from a dense bf16 [N][64] shadow (8B/lane,
// 128B/row -> half the dominant FETCH). Self term stays f32. Epilogue
// writes pre-BN output as f32 (xs) and bf16 (next layer's shadow).
__global__ void __launch_bounds__(256) layer_kernel(
    const float* __restrict__ x_in, int xstride,          // f32 self rows
    const unsigned short* __restrict__ x16in,             // bf16 neighbor rows
    unsigned short* __restrict__ x16out, int wr16,
    const int* __restrict__ seg,     // CSR offsets (N+1)
    const int2* __restrict__ pe,     // (src, w)
    const float* __restrict__ affine /* [128]: scale|shift of input */,
    const float* __restrict__ W1T, const float* __restrict__ b1,
    const float* __restrict__ W2T, const float* __restrict__ b2,
    float* __restrict__ out /* xs base + layer*64, row stride OUTD */,
    float* __restrict__ pstat /* [NLBLK][128]: sum|sumsq partials */) {
    __shared__ float lds[NPB * LDS_PITCH];
    int t = threadIdx.x;
    int lane = t & 63;
    int wid = __builtin_amdgcn_readfirstlane(t >> 6);   // wave id 0..3, SGPR
    int nbase = blockIdx.x * NPB;

    int slot = lane >> 4;            // 0..3: which edge of a 4-group
    int col  = lane & 15;            // which float4 of the row
    const float4* aff4 = (const float4*)affine;
    float4 sc4 = aff4[col];          // scale for cols 4c..4c+3
    float4 sh4 = aff4[16 + col];     // shift

    // ---- Phase 1: gather (16 nodes per wave, node id wave-uniform) ----
    for (int nn = 0; nn < 16; ++nn) {
        int nl = wid * 16 + nn;
        int n = nbase + nl;
        float ax = 0.f, ay = 0.f, az = 0.f, aw = 0.f, wsa = 0.f;
        float bx = 0.f, by = 0.f, bz = 0.f, bw = 0.f, wsb = 0.f;
        if (n < N_NODES) {
            int beg = seg[n];
            int end = seg[n + 1];
#define GBODY(EI, X, Y, Z, W, WS)                                              \
            if ((EI) < end) {                                                  \
                int2 p = pe[EI];                                               \
                float w = __int_as_float(p.y);                                 \
                ushort4 hv =                                                   \
                    ((const ushort4*)(x16in + (size_t)p.x * DIM))[col];        \
                X = fmaf(w, bf2f(hv.x), X); Y = fmaf(w, bf2f(hv.y), Y);        \
                Z = fmaf(w, bf2f(hv.z), Z); W = fmaf(w, bf2f(hv.w), W);        \
                WS += w;                                                       \
            }
            for (int e = beg; e < end; e += 16) {
                int e0 = e + slot;
                GBODY(e0,      ax, ay, az, aw, wsa)
                GBODY(e0 + 4,  bx, by, bz, bw, wsb)
                GBODY(e0 + 8,  ax, ay, az, aw, wsa)
                GBODY(e0 + 12, bx, by, bz, bw, wsb)
            }
#undef GBODY
        }
        float sx = ax + bx, sy = ay + by, sz = az + bz, sw = aw + bw;
        float ws = wsa + wsb;
        // reduce across the 4 slots (lane bits 4,5); all lanes get totals
        sx += __shfl_xor(sx, 16); sy += __shfl_xor(sy, 16);
        sz += __shfl_xor(sz, 16); sw += __shfl_xor(sw, 16);
        ws += __shfl_xor(ws, 16);
        sx += __shfl_xor(sx, 32); sy += __shfl_xor(sy, 32);
        sz += __shfl_xor(sz, 32); sw += __shfl_xor(sw, 32);
        ws += __shfl_xor(ws, 32);
        if (lane < 16) {
            float r0 = 0.f, r1 = 0.f, r2 = 0.f, r3 = 0.f;
            if (n < N_NODES) {
                const float4* xr =
                    (const float4*)(x_in + (size_t)n * xstride) + col;
                float4 s = *xr;                       // self term, f32
                float shw = 1.0f + ws;
                r0 = fmaf(sc4.x, sx + s.x, sh4.x * shw);
                r1 = fmaf(sc4.y, sy + s.y, sh4.y * shw);
                r2 = fmaf(sc4.z, sz + s.z, sh4.z * shw);
                r3 = fmaf(sc4.w, sw + s.w, sh4.w * shw);
            }
            int lb = nl * LDS_PITCH + col * 4;
            lds[lb] = r0; lds[lb + 1] = r1; lds[lb + 2] = r2; lds[lb + 3] = r3;
        }
    }
    __syncthreads();

    // ---- Stage 1 GEMM: hidden = relu(xin @ W1^T + b1) ----
    float h[16];
#pragma unroll
    for (int jj = 0; jj < 16; ++jj) h[jj] = b1[wid * 16 + jj];
#pragma unroll 4
    for (int k = 0; k < DIM; ++k) {
        float xv = lds[lane * LDS_PITCH + k];
        const float* wr = W1T + k * DIM + wid * 16;   // uniform -> s_load
#pragma unroll
        for (int jj = 0; jj < 16; ++jj) h[jj] = fmaf(xv, wr[jj], h[jj]);
    }
#pragma unroll
    for (int jj = 0; jj < 16; ++jj) h[jj] = fmaxf(h[jj], 0.0f);
    __syncthreads();          // all lds (xin) reads done
#pragma unroll
    for (int jj = 0; jj < 16; ++jj) lds[lane * LDS_PITCH + wid * 16 + jj] = h[jj];
    __syncthreads();

    // ---- Stage 2 GEMM: o = relu(hidden @ W2^T + b2) ----
    float o[16];
#pragma unroll
    for (int jj = 0; jj < 16; ++jj) o[jj] = b2[wid * 16 + jj];
#pragma unroll 4
    for (int k = 0; k < DIM; ++k) {
        float hv = lds[lane * LDS_PITCH + k];
        const float* wr = W2T + k * DIM + wid * 16;
#pragma unroll
        for (int jj = 0; jj < 16; ++jj) o[jj] = fmaf(hv, wr[jj], o[jj]);
    }
    int n = nbase + lane;
    bool valid = (n < N_NODES);
#pragma unroll
    for (int jj = 0; jj < 16; ++jj) o[jj] = fmaxf(o[jj], 0.0f);
    if (valid) {
        float* orow = out + (size_t)n * OUTD + wid * 16;
#pragma unroll
        for (int jj = 0; jj < 16; jj += 4) {
            *(float4*)(orow + jj) = make_float4(o[jj], o[jj + 1], o[jj + 2], o[jj + 3]);
        }
        if (wr16) {
            unsigned short* hrow = x16out + (size_t)n * DIM + wid * 16;
#pragma unroll
            for (int jj = 0; jj < 16; jj += 4) {
                ushort4 hq;
                hq.x = f2bf(o[jj]);     hq.y = f2bf(o[jj + 1]);
                hq.z = f2bf(o[jj + 2]); hq.w = f2bf(o[jj + 3]);
                *(ushort4*)(hrow + jj) = hq;
            }
        }
    }

    // ---- BN stat partials: butterfly over 64 lanes; wave wid owns dims
    // [wid*16, wid*16+16). Non-atomic coalesced per-block store.
    float my_s = 0.0f, my_q = 0.0f;
#pragma unroll
    for (int jj = 0; jj < 16; ++jj) {
        float v = valid ? o[jj] : 0.0f;
        float vs = v, vq = v * v;
#pragma unroll
        for (int m = 1; m < 64; m <<= 1) {
            vs += __shfl_xor(vs, m);
            vq += __shfl_xor(vq, m);
        }
        if (lane == jj) { my_s = vs; my_q = vq; }
    }
    if (lane < 16) {
        size_t base = (size_t)blockIdx.x * 128 + wid * 16 + lane;
        pstat[base] = my_s;
        pstat[base + 64] = my_q;
    }
}

// ---------------------------------------------------------------------------
// Reduce per-block BN partials -> scale/shift (bn_prep folded).
__global__ void __launch_bounds__(256) reduce_stats(
    const float* __restrict__ pstat,
    const float* __restrict__ gamma, const float* __restrict__ beta,
    float* __restrict__ ss /* [128]: scale|shift */) {
    __shared__ double part[16][16];
    int b = blockIdx.x;            // 0..7
    int t = threadIdx.x;
    int slot = t & 15;             // 0..7 -> sum(d), 8..15 -> sumsq(d)
    int g = t >> 4;                // group 0..15
    int d = b * 8 + (slot & 7);
    int off = (slot < 8) ? 0 : 64;
    double s = 0.0;
    for (int blk = g; blk < NLBLK; blk += 16)
        s += (double)pstat[(size_t)blk * 128 + off + d];
    part[g][slot] = s;
    __syncthreads();
    if (t < 16) {
        double x = 0.0;
#pragma unroll
        for (int k = 0; k < 16; ++k) x += part[k][t];
        part[0][t] = x;            // column t only -> no hazard
    }
    __syncthreads();
    if (t < 8) {
        int dd = b * 8 + t;
        double mu = part[0][t] / (double)N_NODES;
        double var = part[0][8 + t] / (double)N_NODES - mu * mu;
        float inv = (float)(1.0 / sqrt(var + (double)BN_EPS));
        float sc = gamma[dd] * inv;
        ss[dd] = sc;
        ss[64 + dd] = beta[dd] - (float)mu * sc;
    }
}

// ---------------------------------------------------------------------------
// Final pass: apply BN affine to xs IN PLACE (all 3 layers at once) and
// add-pool per graph. Grid (512 graphs, 4 parts), block 192.
__global__ void bn_pool(float* __restrict__ xs,
                        const int* __restrict__ batch,
                        const float* __restrict__ ss /* [3][128] */,
                        float* __restrict__ pooled) {
    int g = blockIdx.x;
    int part = blockIdx.y;   // 0..3
    int d = threadIdx.x;     // 0..191
    int l = d >> 6, dd = d & 63;
    float sc = ss[l * 128 + dd];
    float sh = ss[l * 128 + 64 + dd];
    int start, end;
    {
        int lo = 0, hi = N_NODES;
        while (lo < hi) { int m = (lo + hi) >> 1; if (batch[m] < g) lo = m + 1; else hi = m; }
        start = lo;
    }
    {
        int lo = start, hi = N_NODES;
        while (lo < hi) { int m = (lo + hi) >> 1; if (batch[m] <= g) lo = m + 1; else hi = m; }
        end = lo;
    }
    float acc = 0.0f;
    for (int n = start + part; n < end; n += 4) {
        float* p = xs + (size_t)n * OUTD + d;
        float v = fmaf(*p, sc, sh);
        *p = v;
        acc += v;
    }
    atomicAdd(&pooled[(size_t)g * OUTD + d], acc);
}

// ---------------------------------------------------------------------------
extern "C" void kernel_launch(void* const* d_in, const int* in_sizes, int n_in,
                              void* d_out, int out_size, void* d_ws, size_t ws_size,
                              hipStream_t stream) {
    const float* x0    = (const float*)d_in[0];
    const int*   ei    = (const int*)d_in[1];
    const float* ew    = (const float*)d_in[2];
    const int*   batch = (const int*)d_in[3];
    const float* W1    = (const float*)d_in[5];
    const float* b1    = (const float*)d_in[6];
    const float* W2    = (const float*)d_in[7];
    const float* b2    = (const float*)d_in[8];
    const float* gamma = (const float*)d_in[9];
    const float* beta  = (const float*)d_in[10];

    float* pooled = (float*)d_out;                      // [512, 192]
    float* xs     = pooled + (size_t)N_GRAPHS * OUTD;   // [100000, 192]

    const int* src = ei;
    const int* dst = ei + N_EDGES;

    // Workspace (~36.5 MB): head = persistent; tail union = {binning scratch}
    // overlapped with {x16 ping-pong} (binning done before to_bf16 runs).
    int2*  pe     = (int2*)d_ws;                        // E  9.6 MB
    int*   seg    = (int*)(pe + N_EDGES);               // N+4
    int*   tot    = seg + N_NODES + 4;                  // NBUK+4
    int*   bstart = tot + NBUK + 4;                     // NBUK+4
    float* W1T    = (float*)(bstart + NBUK + 4);
    float* W2T    = W1T + N_LAYERS * DIM * DIM;
    float* idaff  = W2T + N_LAYERS * DIM * DIM;         // 128 floats
    float* ss     = idaff + 128;                        // 3*128 floats
    float* pstat  = ss + N_LAYERS * 128;                // NLBLK*128 floats
    // union region:
    char* uni = (char*)(pstat + (size_t)NLBLK * 128);
    int2*  pp     = (int2*)uni;                         // E (binning only)
    int*   hist   = (int*)(pp + N_EDGES);               // NPBLK*NBUK
    int*   pbase  = hist + (size_t)NPBLK * NBUK;        // NPBLK*NBUK
    unsigned short* x16a = (unsigned short*)uni;        // N*64 bf16 (12.8 MB)
    unsigned short* x16b = x16a + (size_t)N_NODES * DIM;

    transpose_w<<<(N_LAYERS * DIM * DIM + 255) / 256, 256, 0, stream>>>(
        W1, W2, W1T, W2T, idaff);

    // Two-level binning: contention-free partition -> per-bucket CSR.
    hipMemsetAsync(tot, 0, (NBUK + 4) * sizeof(int), stream);
    part_hist<<<NPBLK, 256, 0, stream>>>(dst, hist, tot);
    scan196<<<1, 256, 0, stream>>>(tot, bstart);
    base_fill<<<NBUK, 256, 0, stream>>>(hist, bstart, pbase);
    part_scatter<<<NPBLK, 256, 0, stream>>>(src, dst, ew, pbase, pp);
    csr_build<<<NBUK, 256, 0, stream>>>(pp, bstart, seg, pe);

    // bf16 shadow of x0 (after binning: frees the union region for x16).
    to_bf16<<<(N_NODES * 16 + 255) / 256, 256, 0, stream>>>(x0, x16a);

    for (int i = 0; i < N_LAYERS; ++i) {
        const float* xin = (i == 0) ? x0 : (xs + (size_t)(i - 1) * DIM);
        int xstride = (i == 0) ? DIM : OUTD;
        const float* affine = (i == 0) ? idaff : (ss + (size_t)(i - 1) * 128);
        const unsigned short* x16in = (i == 1) ? x16b : x16a;
        unsigned short* x16out = (i == 0) ? x16b : x16a;
        int wr16 = (i < N_LAYERS - 1) ? 1 : 0;

        layer_kernel<<<NLBLK, 256, 0, stream>>>(
            xin, xstride, x16in, x16out, wr16, seg, pe, affine,
            W1T + (size_t)i * DIM * DIM, b1 + (size_t)i * DIM,
            W2T + (size_t)i * DIM * DIM, b2 + (size_t)i * DIM,
            xs + (size_t)i * DIM, pstat);

        reduce_stats<<<8, 256, 0, stream>>>(
            pstat, gamma + (size_t)i * DIM, beta + (size_t)i * DIM,
            ss + (size_t)i * 128);
    }

    hipMemsetAsync(pooled, 0, (size_t)N_GRAPHS * OUTD * sizeof(float), stream);
    dim3 pgrid(N_GRAPHS, 4);
    bn_pool<<<pgrid, OUTD, 0, stream>>>(xs, batch, ss, pooled);
}